// Round 9
// baseline (75608.356 us; speedup 1.0000x reference)
//
#include <hip/hip_runtime.h>
#include <hip/hip_bf16.h>

#define H    128
#define E    10
#define V    21
#define O    21
#define LSEQ 32768
#define G3   384            // 3*H

typedef __attribute__((ext_vector_type(8))) short bf16x8;   // 8 bf16 = 4 VGPRs
typedef __attribute__((ext_vector_type(4))) float f32x4;

__device__ __forceinline__ float sigmoidf_(float x) { return 1.0f / (1.0f + __expf(-x)); }
__device__ __forceinline__ float tanhf_(float x)    { return 1.0f - 2.0f / (1.0f + __expf(2.0f * x)); }
__device__ __forceinline__ float bflo(unsigned u) { return __uint_as_float(u << 16); }
__device__ __forceinline__ float bfhi(unsigned u) { return __uint_as_float(u & 0xFFFF0000u); }

__device__ __forceinline__ short f2bf(float f) {
    __hip_bfloat16 h = __float2bfloat16(f);     // RNE
    return __builtin_bit_cast(short, h);
}
__device__ __forceinline__ float sel4(f32x4 v, int c) {
    float x = v[0];
    x = (c == 1) ? v[1] : x;
    x = (c == 2) ? v[2] : x;
    x = (c == 3) ? v[3] : x;
    return x;
}

// ---------------------------------------------------------------------------
// GRU scan via MFMA: 256 threads, 4 waves, 1 wave/SIMD (waves_per_eu(1,1) ->
// full 512-reg unified budget per wave; defeats the R5/R6 pressure shrink).
// Wave w owns 6 tiles: part p in {r,z,n} x tiles {p*8+2w, p*8+2w+1} ->
// gate rows 32w..32w+31 for ALL three gate parts -> in-wave gates with only
// ONE wave's VALU stream per SIMD (R8's failure: 2 waves/SIMD x replicated
// gate code tripled VALUBusy and ate the barrier savings).
// 24 A-frags (96 VGPR) resident; 24 MFMAs/step/wave as 6 independent chains.
// x2 unroll hard-codes hbuf parity; tokens prefetched one pair ahead;
// hiddens staged in a 64-step LDS ring, flushed every 64 steps.
// ---------------------------------------------------------------------------
__global__ void __launch_bounds__(256)
__attribute__((amdgpu_waves_per_eu(1, 1)))
gru_scan(const int*   __restrict__ tokens,
         const float* __restrict__ emb,      // [V,E]
         const float* __restrict__ W_ih,     // [3H,E]
         const float* __restrict__ W_hh,     // [3H,H]
         const float* __restrict__ b_ih,     // [3H]
         const float* __restrict__ b_hh,     // [3H]
         __hip_bfloat16* __restrict__ hiddens,  // ws [L,H] bf16
         float* __restrict__ out,            // fp32 d_out
         int out_size)
{
    __shared__ __align__(16) float X4_sh[V * H * 4];  // [v][row][xr,xz,xn,pad] 42 KB
    __shared__ __align__(16) short hbuf[2][H];        // h (bf16), double-buffered
    __shared__ __align__(16) short ring[64][H];       // 16 KB hiddens staging

    const int t    = threadIdx.x;     // 0..255
    const int w    = t >> 6;          // wave 0..3
    const int lane = t & 63;
    const int quad = lane >> 4;       // 0..3
    const int col  = lane & 15;       // MFMA m / n index
    // gate row for lanes col<8: tile-half = col>>2, reg = col&3
    const int grow = w * 32 + (col >> 2) * 16 + quad * 4 + (col & 3);

    // --- A-fragments: part p, half tt -> tile T = p*8 + 2w + tt, row T*16+col
    // A[m][k]: m = lane&15, k = quad*8 + j
    bf16x8 afrag[3][2][4];
    f32x4  biasf[3][2];
    #pragma unroll
    for (int p = 0; p < 3; ++p) {
        #pragma unroll
        for (int tt = 0; tt < 2; ++tt) {
            const int T   = p * 8 + 2 * w + tt;
            const int row = T * 16 + col;
            #pragma unroll
            for (int kt = 0; kt < 4; ++kt) {
                const float* src = W_hh + row * H + kt * 32 + quad * 8;
                const float4 a = *(const float4*)src;
                const float4 b = *(const float4*)(src + 4);
                bf16x8 f;
                f[0] = f2bf(a.x); f[1] = f2bf(a.y); f[2] = f2bf(a.z); f[3] = f2bf(a.w);
                f[4] = f2bf(b.x); f[5] = f2bf(b.y); f[6] = f2bf(b.z); f[7] = f2bf(b.w);
                afrag[p][tt][kt] = f;
            }
            biasf[p][tt] = *(const f32x4*)(b_hh + T * 16 + quad * 4); // D row=quad*4+reg
        }
    }

    // --- X4_sh[v][r] = (xr, xz, xn, 0) with b_ih folded in ---
    for (int idx = t; idx < V * H; idx += 256) {
        const int v = idx >> 7, r = idx & 127;
        float s0 = b_ih[r], s1 = b_ih[r + 128], s2 = b_ih[r + 256];
        #pragma unroll
        for (int e = 0; e < E; ++e) {
            const float ev = emb[v * E + e];
            s0 = fmaf(W_ih[r * E + e],         ev, s0);
            s1 = fmaf(W_ih[(r + 128) * E + e], ev, s1);
            s2 = fmaf(W_ih[(r + 256) * E + e], ev, s2);
        }
        f32x4 xr = {s0, s1, s2, 0.0f};
        *reinterpret_cast<f32x4*>(&X4_sh[idx * 4]) = xr;
    }
    if (t < H) { hbuf[0][t] = 0; hbuf[1][t] = 0; }
    __syncthreads();

    float h_reg = 0.0f;

#define STEP(PAR, TOK, SLOT)                                                   \
    {                                                                          \
        bf16x8 bfrag[4];                                                       \
        _Pragma("unroll")                                                      \
        for (int kt = 0; kt < 4; ++kt)                                         \
            bfrag[kt] = *reinterpret_cast<const bf16x8*>(                      \
                &hbuf[PAR][kt * 32 + quad * 8]);                               \
        f32x4 xv = {0.0f, 0.0f, 0.0f, 0.0f};                                   \
        if (col < 8)                                                           \
            xv = *reinterpret_cast<const f32x4*>(&X4_sh[((TOK) * H + grow) * 4]); \
        f32x4 acc[3][2];                                                       \
        _Pragma("unroll")                                                      \
        for (int p = 0; p < 3; ++p) {                                          \
            _Pragma("unroll")                                                  \
            for (int tt = 0; tt < 2; ++tt) {                                   \
                acc[p][tt] = biasf[p][tt];                                     \
                _Pragma("unroll")                                              \
                for (int kt = 0; kt < 4; ++kt)                                 \
                    acc[p][tt] = __builtin_amdgcn_mfma_f32_16x16x32_bf16(      \
                        afrag[p][tt][kt], bfrag[kt], acc[p][tt], 0, 0, 0);     \
            }                                                                  \
        }                                                                      \
        if (col < 8) {                                                         \
            const int rg = col & 3, th = col >> 2;                             \
            const float gr = sel4(acc[0][th], rg);                             \
            const float gz = sel4(acc[1][th], rg);                             \
            const float gn = sel4(acc[2][th], rg);                             \
            const float rr = sigmoidf_(xv.x + gr);                             \
            const float zz = sigmoidf_(xv.y + gz);                             \
            const float nn = tanhf_(fmaf(rr, gn, xv.z));                       \
            h_reg = fmaf(zz, h_reg - nn, nn);                                  \
            const short hbv = f2bf(h_reg);                                     \
            hbuf[(PAR) ^ 1][grow] = hbv;                                       \
            ring[SLOT][grow] = hbv;                                            \
        }                                                                      \
        __syncthreads();                                                       \
    }

    int tok0 = tokens[0];
    int tok1 = tokens[1];
    for (int l = 0; l < LSEQ; l += 2) {
        const int i2 = l + 2, i3 = l + 3;
        const int tok2 = tokens[(i2 < LSEQ) ? i2 : 0];   // consumed next pair
        const int tok3 = tokens[(i3 < LSEQ) ? i3 : 0];
        const int slot = l & 63;

        STEP(0, tok0, slot)
        STEP(1, tok1, slot + 1)

        if (slot == 62) {        // ring full: flush 64 steps -> global
            const uint4* rsrc = (const uint4*)&ring[0][0];   // 1024 uint4
            uint4* dst = (uint4*)(hiddens + (size_t)(l - 62) * H);
            dst[t]       = rsrc[t];
            dst[t + 256] = rsrc[t + 256];
            dst[t + 512] = rsrc[t + 512];
            dst[t + 768] = rsrc[t + 768];
            __syncthreads();     // slot 0 is rewritten next step
        }
        tok0 = tok2; tok1 = tok3;
    }
#undef STEP

    // last_hidden = final H elements of d_out (fp32)
    if (col < 8) out[out_size - H + grow] = h_reg;
}

// ---------------------------------------------------------------------------
// Decode post-pass: logits = hiddens @ W_dec^T + b_dec ; log_softmax ; fp32.
// One sequence row per thread, 128 blocks x 256 threads. W_dec in LDS.
// ---------------------------------------------------------------------------
__global__ void __launch_bounds__(256)
gru_decode(const __hip_bfloat16* __restrict__ hiddens, // [L,H] bf16
           const float* __restrict__ W_dec,            // [O,H]
           const float* __restrict__ b_dec,            // [O]
           float* __restrict__ out)                    // [L,O] fp32
{
    __shared__ float wd[O * H];
    __shared__ float bd[O];
    const int t = threadIdx.x;
    for (int i = t; i < O * H; i += 256) wd[i] = W_dec[i];
    if (t < O) bd[t] = b_dec[t];
    __syncthreads();

    const int row = blockIdx.x * 256 + t;    // grid = L/256
    float logit[O];
    #pragma unroll
    for (int o = 0; o < O; ++o) logit[o] = bd[o];

    const uint4* hp = (const uint4*)(hiddens + (size_t)row * H);
    #pragma unroll
    for (int j = 0; j < H / 8; ++j) {
        const uint4 u = hp[j];
        const float h0 = bflo(u.x), h1 = bfhi(u.x);
        const float h2 = bflo(u.y), h3 = bfhi(u.y);
        const float h4 = bflo(u.z), h5 = bfhi(u.z);
        const float h6 = bflo(u.w), h7 = bfhi(u.w);
        const int c = j * 8;
        #pragma unroll
        for (int o = 0; o < O; ++o) {
            const float* wr = wd + o * H + c;    // uniform addr -> broadcast
            float a = logit[o];
            a = fmaf(wr[0], h0, a); a = fmaf(wr[1], h1, a);
            a = fmaf(wr[2], h2, a); a = fmaf(wr[3], h3, a);
            a = fmaf(wr[4], h4, a); a = fmaf(wr[5], h5, a);
            a = fmaf(wr[6], h6, a); a = fmaf(wr[7], h7, a);
            logit[o] = a;
        }
    }

    float m = logit[0];
    #pragma unroll
    for (int o = 1; o < O; ++o) m = fmaxf(m, logit[o]);
    float s = 0.0f;
    #pragma unroll
    for (int o = 0; o < O; ++o) s += __expf(logit[o] - m);
    const float lse = m + __logf(s);
    #pragma unroll
    for (int o = 0; o < O; ++o)
        out[(size_t)row * O + o] = logit[o] - lse;
}

extern "C" void kernel_launch(void* const* d_in, const int* in_sizes, int n_in,
                              void* d_out, int out_size, void* d_ws, size_t ws_size,
                              hipStream_t stream) {
    const int*   tokens = (const int*)d_in[0];
    const float* emb    = (const float*)d_in[1];
    const float* W_ih   = (const float*)d_in[2];
    const float* W_hh   = (const float*)d_in[3];
    const float* b_ih   = (const float*)d_in[4];
    const float* b_hh   = (const float*)d_in[5];
    const float* W_dec  = (const float*)d_in[6];
    const float* b_dec  = (const float*)d_in[7];
    float* out = (float*)d_out;
    __hip_bfloat16* hiddens = (__hip_bfloat16*)d_ws;   // L*H*2 = 8.4 MB

    gru_scan<<<1, 256, 0, stream>>>(tokens, emb, W_ih, W_hh, b_ih, b_hh,
                                    hiddens, out, out_size);
    gru_decode<<<LSEQ / 256, 256, 0, stream>>>(hiddens, W_dec, b_dec, out);
}

// Round 11
// 14524.449 us; speedup vs baseline: 5.2056x; 5.2056x over previous
//
#include <hip/hip_runtime.h>
#include <hip/hip_bf16.h>

#define H    128
#define E    10
#define V    21
#define O    21
#define LSEQ 32768
#define G3   384            // 3*H

typedef __attribute__((ext_vector_type(8))) short bf16x8;   // 8 bf16 = 4 VGPRs
typedef __attribute__((ext_vector_type(4))) float f32x4;

__device__ __forceinline__ float sigmoidf_(float x) { return 1.0f / (1.0f + __expf(-x)); }
__device__ __forceinline__ float tanhf_(float x)    { return 1.0f - 2.0f / (1.0f + __expf(2.0f * x)); }
__device__ __forceinline__ float bflo(unsigned u) { return __uint_as_float(u << 16); }
__device__ __forceinline__ float bfhi(unsigned u) { return __uint_as_float(u & 0xFFFF0000u); }

__device__ __forceinline__ short f2bf(float f) {
    __hip_bfloat16 h = __float2bfloat16(f);     // RNE
    return __builtin_bit_cast(short, h);
}

// ---------------------------------------------------------------------------
// GRU scan via TRANSPOSED MFMA, R8-bit-exact numerics.
// 512 threads (8 waves), waves_per_eu(2,2) — R8's proven occupancy recipe.
// gh = h^T · W_hh^T: A = h replicated over rows, B = W_hh^T (same register
// data as R8's A-frags, swapped operand slot). Per-element MFMA chain
// b_hh[g] + sum_k W[g][k]*h[k] is IDENTICAL to R8's (operand swap permutes
// which lane holds an element, not the element's scalar chain), so the h
// trajectory reproduces R8's bit-for-bit -> absmax 0.015625 (R10's failure
// was folding b_hh into the fp32 X-table: changed rounding pattern, chaotic
// recurrence drew a worse final-h sample, 0.0679 > 0.0634).
// b_hh enters as persistent C-operand quad {b,b,b,b}, b = b_hh[T*16+col]
// (C[m][n] = b_hh[T*16+n] for all m). No sel4: D row index = lane&15, reg 0.
// One barrier/step; h double-buffered; 64-step ring flush.
// ---------------------------------------------------------------------------
__global__ void __launch_bounds__(512)
__attribute__((amdgpu_waves_per_eu(2, 2)))
gru_scan(const int*   __restrict__ tokens,
         const float* __restrict__ emb,      // [V,E]
         const float* __restrict__ W_ih,     // [3H,E]
         const float* __restrict__ W_hh,     // [3H,H]
         const float* __restrict__ b_ih,     // [3H]
         const float* __restrict__ b_hh,     // [3H]
         __hip_bfloat16* __restrict__ hiddens,  // ws [L,H] bf16
         float* __restrict__ out,            // fp32 d_out
         int out_size)
{
    __shared__ __align__(16) float X4_sh[V * H * 4];  // [v][row][xr,xz,xn,pad] 42 KB
    __shared__ __align__(16) short hbuf[2][H];        // h (bf16), double-buffered
    __shared__ __align__(16) short ring[64][H];       // 16 KB hiddens staging

    const int t    = threadIdx.x;     // 0..511
    const int w    = t >> 6;          // wave 0..7
    const int lane = t & 63;
    const int quad = lane >> 4;       // 0..3
    const int col  = lane & 15;       // MFMA n index == gh row within tile
    const int grow = w * 16 + lane;   // gate row (valid when lane<16)

    // --- B-fragments (W_hh^T), resident: part p -> tile T = w + 8p ---
    // B[k][n]: k = quad*8 + j, n = col  ->  lane loads W_hh[T*16+col][kt*32+quad*8+j]
    bf16x8 wfrag[3][4];
    f32x4  biasq[3];                  // C-operand: {b,b,b,b}, b = b_hh[T*16+col]
    #pragma unroll
    for (int p = 0; p < 3; ++p) {
        const int T   = w + 8 * p;
        const int row = T * 16 + col;
        #pragma unroll
        for (int kt = 0; kt < 4; ++kt) {
            const float* src = W_hh + row * H + kt * 32 + quad * 8;
            const float4 a = *(const float4*)src;
            const float4 b = *(const float4*)(src + 4);
            bf16x8 f;
            f[0] = f2bf(a.x); f[1] = f2bf(a.y); f[2] = f2bf(a.z); f[3] = f2bf(a.w);
            f[4] = f2bf(b.x); f[5] = f2bf(b.y); f[6] = f2bf(b.z); f[7] = f2bf(b.w);
            wfrag[p][kt] = f;
        }
        const float bb = b_hh[row];
        biasq[p] = (f32x4){bb, bb, bb, bb};
    }

    // --- X4_sh[v][r] = (xr, xz, xn, 0) with b_ih folded in (R8-identical) ---
    for (int idx = t; idx < V * H; idx += 512) {
        const int v = idx >> 7, r = idx & 127;
        float s0 = b_ih[r], s1 = b_ih[r + 128], s2 = b_ih[r + 256];
        #pragma unroll
        for (int e = 0; e < E; ++e) {
            const float ev = emb[v * E + e];
            s0 = fmaf(W_ih[r * E + e],         ev, s0);
            s1 = fmaf(W_ih[(r + 128) * E + e], ev, s1);
            s2 = fmaf(W_ih[(r + 256) * E + e], ev, s2);
        }
        f32x4 xr = {s0, s1, s2, 0.0f};
        *reinterpret_cast<f32x4*>(&X4_sh[idx * 4]) = xr;
    }
    if (t < H) { hbuf[0][t] = 0; hbuf[1][t] = 0; }
    __syncthreads();

    float h_reg = 0.0f;

#define STEP(PAR, TOK, SLOT)                                                   \
    {                                                                          \
        bf16x8 hfrag[4];   /* A: h[k], identical for all rows m (broadcast) */ \
        _Pragma("unroll")                                                      \
        for (int kt = 0; kt < 4; ++kt)                                         \
            hfrag[kt] = *reinterpret_cast<const bf16x8*>(                      \
                &hbuf[PAR][kt * 32 + quad * 8]);                               \
        f32x4 xv = {0.0f, 0.0f, 0.0f, 0.0f};                                   \
        if (lane < 16)                                                         \
            xv = *reinterpret_cast<const f32x4*>(&X4_sh[((TOK) * H + grow) * 4]); \
        f32x4 accr = biasq[0], accz = biasq[1], accn = biasq[2];               \
        _Pragma("unroll")                                                      \
        for (int kt = 0; kt < 4; ++kt) {                                       \
            accr = __builtin_amdgcn_mfma_f32_16x16x32_bf16(hfrag[kt], wfrag[0][kt], accr, 0, 0, 0); \
            accz = __builtin_amdgcn_mfma_f32_16x16x32_bf16(hfrag[kt], wfrag[1][kt], accz, 0, 0, 0); \
            accn = __builtin_amdgcn_mfma_f32_16x16x32_bf16(hfrag[kt], wfrag[2][kt], accn, 0, 0, 0); \
        }                                                                      \
        if (lane < 16) {                                                       \
            const float rr = sigmoidf_(xv.x + accr[0]);                        \
            const float zz = sigmoidf_(xv.y + accz[0]);                        \
            const float nn = tanhf_(fmaf(rr, accn[0], xv.z));                  \
            h_reg = fmaf(zz, h_reg - nn, nn);                                  \
            const short hbv = f2bf(h_reg);                                     \
            hbuf[(PAR) ^ 1][grow] = hbv;                                       \
            ring[SLOT][grow] = hbv;                                            \
        }                                                                      \
        __syncthreads();                                                       \
    }

    int tok0 = tokens[0];
    int tok1 = tokens[1];
    for (int l = 0; l < LSEQ; l += 2) {
        const int i2 = l + 2, i3 = l + 3;
        const int tok2 = tokens[(i2 < LSEQ) ? i2 : 0];   // consumed next pair
        const int tok3 = tokens[(i3 < LSEQ) ? i3 : 0];
        const int slot = l & 63;

        STEP(0, tok0, slot)
        STEP(1, tok1, slot + 1)

        if (slot == 62) {        // ring full: flush 64 steps -> global
            const uint4* rsrc = (const uint4*)&ring[0][0];   // 1024 uint4
            uint4* dst = (uint4*)(hiddens + (size_t)(l - 62) * H);
            dst[t]       = rsrc[t];
            dst[t + 512] = rsrc[t + 512];
            __syncthreads();     // slot 0 is rewritten next step
        }
        tok0 = tok2; tok1 = tok3;
    }
#undef STEP

    // last_hidden = final H elements of d_out (fp32)
    if (lane < 16) out[out_size - H + grow] = h_reg;
}

// ---------------------------------------------------------------------------
// Decode post-pass: logits = hiddens @ W_dec^T + b_dec ; log_softmax ; fp32.
// One sequence row per thread, 128 blocks x 256 threads. W_dec in LDS.
// ---------------------------------------------------------------------------
__global__ void __launch_bounds__(256)
gru_decode(const __hip_bfloat16* __restrict__ hiddens, // [L,H] bf16
           const float* __restrict__ W_dec,            // [O,H]
           const float* __restrict__ b_dec,            // [O]
           float* __restrict__ out)                    // [L,O] fp32
{
    __shared__ float wd[O * H];
    __shared__ float bd[O];
    const int t = threadIdx.x;
    for (int i = t; i < O * H; i += 256) wd[i] = W_dec[i];
    if (t < O) bd[t] = b_dec[t];
    __syncthreads();

    const int row = blockIdx.x * 256 + t;    // grid = L/256
    float logit[O];
    #pragma unroll
    for (int o = 0; o < O; ++o) logit[o] = bd[o];

    const uint4* hp = (const uint4*)(hiddens + (size_t)row * H);
    #pragma unroll
    for (int j = 0; j < H / 8; ++j) {
        const uint4 u = hp[j];
        const float h0 = bflo(u.x), h1 = bfhi(u.x);
        const float h2 = bflo(u.y), h3 = bfhi(u.y);
        const float h4 = bflo(u.z), h5 = bfhi(u.z);
        const float h6 = bflo(u.w), h7 = bfhi(u.w);
        const int c = j * 8;
        #pragma unroll
        for (int o = 0; o < O; ++o) {
            const float* wr = wd + o * H + c;    // uniform addr -> broadcast
            float a = logit[o];
            a = fmaf(wr[0], h0, a); a = fmaf(wr[1], h1, a);
            a = fmaf(wr[2], h2, a); a = fmaf(wr[3], h3, a);
            a = fmaf(wr[4], h4, a); a = fmaf(wr[5], h5, a);
            a = fmaf(wr[6], h6, a); a = fmaf(wr[7], h7, a);
            logit[o] = a;
        }
    }

    float m = logit[0];
    #pragma unroll
    for (int o = 1; o < O; ++o) m = fmaxf(m, logit[o]);
    float s = 0.0f;
    #pragma unroll
    for (int o = 0; o < O; ++o) s += __expf(logit[o] - m);
    const float lse = m + __logf(s);
    #pragma unroll
    for (int o = 0; o < O; ++o)
        out[(size_t)row * O + o] = logit[o] - lse;
}

extern "C" void kernel_launch(void* const* d_in, const int* in_sizes, int n_in,
                              void* d_out, int out_size, void* d_ws, size_t ws_size,
                              hipStream_t stream) {
    const int*   tokens = (const int*)d_in[0];
    const float* emb    = (const float*)d_in[1];
    const float* W_ih   = (const float*)d_in[2];
    const float* W_hh   = (const float*)d_in[3];
    const float* b_ih   = (const float*)d_in[4];
    const float* b_hh   = (const float*)d_in[5];
    const float* W_dec  = (const float*)d_in[6];
    const float* b_dec  = (const float*)d_in[7];
    float* out = (float*)d_out;
    __hip_bfloat16* hiddens = (__hip_bfloat16*)d_ws;   // L*H*2 = 8.4 MB

    gru_scan<<<1, 512, 0, stream>>>(tokens, emb, W_ih, W_hh, b_ih, b_hh,
                                    hiddens, out, out_size);
    gru_decode<<<LSEQ / 256, 256, 0, stream>>>(hiddens, W_dec, b_dec, out);
}

// Round 12
// 13874.361 us; speedup vs baseline: 5.4495x; 1.0469x over previous
//
#include <hip/hip_runtime.h>
#include <hip/hip_bf16.h>

#define H    128
#define E    10
#define V    21
#define O    21
#define LSEQ 32768
#define G3   384            // 3*H

typedef __attribute__((ext_vector_type(8))) short bf16x8;   // 8 bf16 = 4 VGPRs
typedef __attribute__((ext_vector_type(4))) float f32x4;

__device__ __forceinline__ float sigmoidf_(float x) { return 1.0f / (1.0f + __expf(-x)); }
__device__ __forceinline__ float tanhf_(float x)    { return 1.0f - 2.0f / (1.0f + __expf(2.0f * x)); }
__device__ __forceinline__ float bflo(unsigned u) { return __uint_as_float(u << 16); }
__device__ __forceinline__ float bfhi(unsigned u) { return __uint_as_float(u & 0xFFFF0000u); }

__device__ __forceinline__ short f2bf(float f) {
    __hip_bfloat16 h = __float2bfloat16(f);     // RNE
    return __builtin_bit_cast(short, h);
}

// ---------------------------------------------------------------------------
// GRU scan via transposed MFMA: 256 threads, 4 waves, 1 wave/SIMD
// (waves_per_eu(1,1) -> full 512-reg unified budget).
// Wave w owns tiles {p*8+2w, p*8+2w+1} for parts p=r,z,n: 6 independent
// 4-deep MFMA chains (24 MFMAs/step), covering gh rows 32w..32w+31 for all
// three gates -> in-wave gates on 32 lanes, ONE static cndmask per part
// (lane<16 ? tt0 : tt1). NO dynamic register-array indexing anywhere —
// R9's VALU explosion (690 instrs/wave/step) was sel4(acc[p][th],rg) with
// runtime th,rg; R11 (static) behaved, so this config is now safe.
// Per-SIMD issue/step: ONE wave's VALU (~60 instrs) + 24 MFMA, vs R11's
// two replicated streams (580 VALU-cyc/SIMD/step).
// Numerics bit-exact vs R8/R11: b_hh as MFMA C-operand, b_ih-only X table,
// identical per-element chains and gate formula.
// One barrier/step; h double-buffered; 64-step ring flush.
// ---------------------------------------------------------------------------
__global__ void __launch_bounds__(256)
__attribute__((amdgpu_waves_per_eu(1, 1)))
gru_scan(const int*   __restrict__ tokens,
         const float* __restrict__ emb,      // [V,E]
         const float* __restrict__ W_ih,     // [3H,E]
         const float* __restrict__ W_hh,     // [3H,H]
         const float* __restrict__ b_ih,     // [3H]
         const float* __restrict__ b_hh,     // [3H]
         __hip_bfloat16* __restrict__ hiddens,  // ws [L,H] bf16
         float* __restrict__ out,            // fp32 d_out
         int out_size)
{
    __shared__ __align__(16) float X4_sh[V * H * 4];  // [v][row][xr,xz,xn,pad] 42 KB
    __shared__ __align__(16) short hbuf[2][H];        // h (bf16), double-buffered
    __shared__ __align__(16) short ring[64][H];       // 16 KB hiddens staging

    const int t    = threadIdx.x;     // 0..255
    const int w    = t >> 6;          // wave 0..3
    const int lane = t & 63;
    const int quad = lane >> 4;       // 0..3
    const int col  = lane & 15;       // MFMA n index == gh row within tile
    const int grow = w * 32 + lane;   // gate row (valid when lane<32)

    // --- B-fragments (W_hh^T), resident: part p, half tt -> tile p*8+2w+tt ---
    // B[k][n]: k = quad*8 + j, n = col -> lane loads W_hh[T*16+col][kt*32+quad*8+j]
    bf16x8 wfrag[3][2][4];
    f32x4  biasq[3][2];               // C-operand: {b,b,b,b}, b = b_hh[T*16+col]
    #pragma unroll
    for (int p = 0; p < 3; ++p) {
        #pragma unroll
        for (int tt = 0; tt < 2; ++tt) {
            const int T   = p * 8 + 2 * w + tt;
            const int row = T * 16 + col;
            #pragma unroll
            for (int kt = 0; kt < 4; ++kt) {
                const float* src = W_hh + row * H + kt * 32 + quad * 8;
                const float4 a = *(const float4*)src;
                const float4 b = *(const float4*)(src + 4);
                bf16x8 f;
                f[0] = f2bf(a.x); f[1] = f2bf(a.y); f[2] = f2bf(a.z); f[3] = f2bf(a.w);
                f[4] = f2bf(b.x); f[5] = f2bf(b.y); f[6] = f2bf(b.z); f[7] = f2bf(b.w);
                wfrag[p][tt][kt] = f;
            }
            const float bb = b_hh[row];
            biasq[p][tt] = (f32x4){bb, bb, bb, bb};
        }
    }

    // --- X4_sh[v][r] = (xr, xz, xn, 0) with b_ih folded in (R8-identical) ---
    for (int idx = t; idx < V * H; idx += 256) {
        const int v = idx >> 7, r = idx & 127;
        float s0 = b_ih[r], s1 = b_ih[r + 128], s2 = b_ih[r + 256];
        #pragma unroll
        for (int e = 0; e < E; ++e) {
            const float ev = emb[v * E + e];
            s0 = fmaf(W_ih[r * E + e],         ev, s0);
            s1 = fmaf(W_ih[(r + 128) * E + e], ev, s1);
            s2 = fmaf(W_ih[(r + 256) * E + e], ev, s2);
        }
        f32x4 xr = {s0, s1, s2, 0.0f};
        *reinterpret_cast<f32x4*>(&X4_sh[idx * 4]) = xr;
    }
    if (t < H) { hbuf[0][t] = 0; hbuf[1][t] = 0; }
    __syncthreads();

    float h_reg = 0.0f;

#define STEP(PAR, TOK, SLOT)                                                   \
    {                                                                          \
        bf16x8 hfrag[4];   /* A: h[k], identical for all rows m (broadcast) */ \
        _Pragma("unroll")                                                      \
        for (int kt = 0; kt < 4; ++kt)                                         \
            hfrag[kt] = *reinterpret_cast<const bf16x8*>(                      \
                &hbuf[PAR][kt * 32 + quad * 8]);                               \
        f32x4 xv = {0.0f, 0.0f, 0.0f, 0.0f};                                   \
        if (lane < 32)                                                         \
            xv = *reinterpret_cast<const f32x4*>(&X4_sh[((TOK) * H + grow) * 4]); \
        f32x4 ar0 = biasq[0][0], ar1 = biasq[0][1];                            \
        f32x4 az0 = biasq[1][0], az1 = biasq[1][1];                            \
        f32x4 an0 = biasq[2][0], an1 = biasq[2][1];                            \
        _Pragma("unroll")                                                      \
        for (int kt = 0; kt < 4; ++kt) {                                       \
            ar0 = __builtin_amdgcn_mfma_f32_16x16x32_bf16(hfrag[kt], wfrag[0][0][kt], ar0, 0, 0, 0); \
            ar1 = __builtin_amdgcn_mfma_f32_16x16x32_bf16(hfrag[kt], wfrag[0][1][kt], ar1, 0, 0, 0); \
            az0 = __builtin_amdgcn_mfma_f32_16x16x32_bf16(hfrag[kt], wfrag[1][0][kt], az0, 0, 0, 0); \
            az1 = __builtin_amdgcn_mfma_f32_16x16x32_bf16(hfrag[kt], wfrag[1][1][kt], az1, 0, 0, 0); \
            an0 = __builtin_amdgcn_mfma_f32_16x16x32_bf16(hfrag[kt], wfrag[2][0][kt], an0, 0, 0, 0); \
            an1 = __builtin_amdgcn_mfma_f32_16x16x32_bf16(hfrag[kt], wfrag[2][1][kt], an1, 0, 0, 0); \
        }                                                                      \
        if (lane < 32) {                                                       \
            const float gr = (lane < 16) ? ar0[0] : ar1[0];  /* static regs */ \
            const float gz = (lane < 16) ? az0[0] : az1[0];                    \
            const float gn = (lane < 16) ? an0[0] : an1[0];                    \
            const float rr = sigmoidf_(xv.x + gr);                             \
            const float zz = sigmoidf_(xv.y + gz);                             \
            const float nn = tanhf_(fmaf(rr, gn, xv.z));                       \
            h_reg = fmaf(zz, h_reg - nn, nn);                                  \
            const short hbv = f2bf(h_reg);                                     \
            hbuf[(PAR) ^ 1][grow] = hbv;                                       \
            ring[SLOT][grow] = hbv;                                            \
        }                                                                      \
        __syncthreads();                                                       \
    }

    int tok0 = tokens[0];
    int tok1 = tokens[1];
    for (int l = 0; l < LSEQ; l += 2) {
        const int i2 = l + 2, i3 = l + 3;
        const int tok2 = tokens[(i2 < LSEQ) ? i2 : 0];   // consumed next pair
        const int tok3 = tokens[(i3 < LSEQ) ? i3 : 0];
        const int slot = l & 63;

        STEP(0, tok0, slot)
        STEP(1, tok1, slot + 1)

        if (slot == 62) {        // ring full: flush 64 steps -> global
            const uint4* rsrc = (const uint4*)&ring[0][0];   // 1024 uint4
            uint4* dst = (uint4*)(hiddens + (size_t)(l - 62) * H);
            dst[t]       = rsrc[t];
            dst[t + 256] = rsrc[t + 256];
            dst[t + 512] = rsrc[t + 512];
            dst[t + 768] = rsrc[t + 768];
            __syncthreads();     // slot 0 is rewritten next step
        }
        tok0 = tok2; tok1 = tok3;
    }
#undef STEP

    // last_hidden = final H elements of d_out (fp32)
    if (lane < 32) out[out_size - H + grow] = h_reg;
}

// ---------------------------------------------------------------------------
// Decode post-pass: logits = hiddens @ W_dec^T + b_dec ; log_softmax ; fp32.
// One sequence row per thread, 128 blocks x 256 threads. W_dec in LDS.
// ---------------------------------------------------------------------------
__global__ void __launch_bounds__(256)
gru_decode(const __hip_bfloat16* __restrict__ hiddens, // [L,H] bf16
           const float* __restrict__ W_dec,            // [O,H]
           const float* __restrict__ b_dec,            // [O]
           float* __restrict__ out)                    // [L,O] fp32
{
    __shared__ float wd[O * H];
    __shared__ float bd[O];
    const int t = threadIdx.x;
    for (int i = t; i < O * H; i += 256) wd[i] = W_dec[i];
    if (t < O) bd[t] = b_dec[t];
    __syncthreads();

    const int row = blockIdx.x * 256 + t;    // grid = L/256
    float logit[O];
    #pragma unroll
    for (int o = 0; o < O; ++o) logit[o] = bd[o];

    const uint4* hp = (const uint4*)(hiddens + (size_t)row * H);
    #pragma unroll
    for (int j = 0; j < H / 8; ++j) {
        const uint4 u = hp[j];
        const float h0 = bflo(u.x), h1 = bfhi(u.x);
        const float h2 = bflo(u.y), h3 = bfhi(u.y);
        const float h4 = bflo(u.z), h5 = bfhi(u.z);
        const float h6 = bflo(u.w), h7 = bfhi(u.w);
        const int c = j * 8;
        #pragma unroll
        for (int o = 0; o < O; ++o) {
            const float* wr = wd + o * H + c;    // uniform addr -> broadcast
            float a = logit[o];
            a = fmaf(wr[0], h0, a); a = fmaf(wr[1], h1, a);
            a = fmaf(wr[2], h2, a); a = fmaf(wr[3], h3, a);
            a = fmaf(wr[4], h4, a); a = fmaf(wr[5], h5, a);
            a = fmaf(wr[6], h6, a); a = fmaf(wr[7], h7, a);
            logit[o] = a;
        }
    }

    float m = logit[0];
    #pragma unroll
    for (int o = 1; o < O; ++o) m = fmaxf(m, logit[o]);
    float s = 0.0f;
    #pragma unroll
    for (int o = 0; o < O; ++o) s += __expf(logit[o] - m);
    const float lse = m + __logf(s);
    #pragma unroll
    for (int o = 0; o < O; ++o)
        out[(size_t)row * O + o] = logit[o] - lse;
}

extern "C" void kernel_launch(void* const* d_in, const int* in_sizes, int n_in,
                              void* d_out, int out_size, void* d_ws, size_t ws_size,
                              hipStream_t stream) {
    const int*   tokens = (const int*)d_in[0];
    const float* emb    = (const float*)d_in[1];
    const float* W_ih   = (const float*)d_in[2];
    const float* W_hh   = (const float*)d_in[3];
    const float* b_ih   = (const float*)d_in[4];
    const float* b_hh   = (const float*)d_in[5];
    const float* W_dec  = (const float*)d_in[6];
    const float* b_dec  = (const float*)d_in[7];
    float* out = (float*)d_out;
    __hip_bfloat16* hiddens = (__hip_bfloat16*)d_ws;   // L*H*2 = 8.4 MB

    gru_scan<<<1, 256, 0, stream>>>(tokens, emb, W_ih, W_hh, b_ih, b_hh,
                                    hiddens, out, out_size);
    gru_decode<<<LSEQ / 256, 256, 0, stream>>>(hiddens, W_dec, b_dec, out);
}